// Round 1
// baseline (2424.975 us; speedup 1.0000x reference)
//
#include <hip/hip_runtime.h>
#include <cfloat>

#define NTOK 65536
#define DIM  512
#define KCB  1024
#define TAU  0.05f
#define REF_CAP 8192

// ---------------- ws layout (bytes) ----------------
// 0        : idx       int[NTOK]      262144
// 262144   : counts    f32[KCB]       4096
// 266240   : esum      f32[KCB*DIM]   2097152
// 2363392  : esq       f32[KCB]       4096
// 2367488  : refCount  int (16B pad)
// 2367504  : refList   int[REF_CAP]   32768
// 2400272  : n         f32

__global__ __launch_bounds__(256) void esq_kernel(const float* __restrict__ E,
                                                  float* __restrict__ esq)
{
    const int lane = threadIdx.x & 63;
    const int wv   = threadIdx.x >> 6;
    const int k    = blockIdx.x * 4 + wv;
    const float* er = E + (size_t)k * DIM + lane * 8;
    float4 a = *(const float4*)er;
    float4 b = *(const float4*)(er + 4);
    float s = a.x*a.x + a.y*a.y + a.z*a.z + a.w*a.w
            + b.x*b.x + b.y*b.y + b.z*b.z + b.w*b.w;
    for (int off = 32; off > 0; off >>= 1) s += __shfl_down(s, off, 64);
    if (lane == 0) esq[k] = s;
}

// 64 tokens x 1024 codes per block; K staged in 64-wide chunks.
// dist' = ||e||^2 - 2 z.e  (per-token const ||z||^2 dropped: argmin-invariant)
__global__ __launch_bounds__(256) void score_kernel(
    const float* __restrict__ z, const float* __restrict__ E,
    const float* __restrict__ esq,
    int* __restrict__ idx_ws, float* __restrict__ idx_out,
    int* __restrict__ refCount, int* __restrict__ refList)
{
    __shared__ float zs[64][68];   // [token][d_local], pad 68 for bank spread
    __shared__ float es[64][64];   // [d_local][code_local] (transposed)
    const int tid = threadIdx.x;
    const int blk = blockIdx.x;
    const int ty = tid >> 4;       // 0..15 -> 4 tokens each
    const int tx = tid & 15;       // 0..15 -> 4 codes each
    const int rS = tid >> 2;       // staging row 0..63
    const int q0 = tid & 3;

    const float* zblk = z + (size_t)blk * 64 * DIM;

    float d1[4], d2[4]; int i1[4];
    #pragma unroll
    for (int i = 0; i < 4; ++i) { d1[i] = FLT_MAX; d2[i] = FLT_MAX; i1[i] = KCB; }

    for (int cc = 0; cc < 16; ++cc) {
        const int code0 = cc * 64;
        float acc[4][4] = {};
        for (int dk = 0; dk < 8; ++dk) {
            const int dbase = dk * 64;
            __syncthreads();
            #pragma unroll
            for (int m = 0; m < 4; ++m) {
                const int q = q0 + m * 4;
                float4 vz = *(const float4*)(zblk + (size_t)rS * DIM + dbase + q * 4);
                *(float4*)&zs[rS][q * 4] = vz;
                float4 ve = *(const float4*)(E + (size_t)(code0 + rS) * DIM + dbase + q * 4);
                es[q*4+0][rS] = ve.x;
                es[q*4+1][rS] = ve.y;
                es[q*4+2][rS] = ve.z;
                es[q*4+3][rS] = ve.w;
            }
            __syncthreads();
            #pragma unroll 4
            for (int dq = 0; dq < 16; ++dq) {
                float zr[4][4];
                #pragma unroll
                for (int i = 0; i < 4; ++i) {
                    float4 t = *(const float4*)&zs[ty*4+i][dq*4];
                    zr[i][0]=t.x; zr[i][1]=t.y; zr[i][2]=t.z; zr[i][3]=t.w;
                }
                #pragma unroll
                for (int dd = 0; dd < 4; ++dd) {
                    float4 ev = *(const float4*)&es[dq*4+dd][tx*4];
                    #pragma unroll
                    for (int i = 0; i < 4; ++i) {
                        const float zz = zr[i][dd];
                        acc[i][0] = fmaf(zz, ev.x, acc[i][0]);
                        acc[i][1] = fmaf(zz, ev.y, acc[i][1]);
                        acc[i][2] = fmaf(zz, ev.z, acc[i][2]);
                        acc[i][3] = fmaf(zz, ev.w, acc[i][3]);
                    }
                }
            }
        }
        #pragma unroll
        for (int j = 0; j < 4; ++j) {
            const int code = code0 + tx * 4 + j;
            const float ej = esq[code];
            #pragma unroll
            for (int i = 0; i < 4; ++i) {
                const float dist = ej - 2.0f * acc[i][j];
                if (dist < d1[i] || (dist == d1[i] && code < i1[i])) {
                    d2[i] = d1[i]; d1[i] = dist; i1[i] = code;
                } else {
                    d2[i] = fminf(d2[i], dist);
                }
            }
        }
    }
    // merge top-2 across the 16 tx lanes (low 4 lane bits)
    #pragma unroll
    for (int off = 1; off < 16; off <<= 1) {
        #pragma unroll
        for (int i = 0; i < 4; ++i) {
            const float od1 = __shfl_xor(d1[i], off, 64);
            const int   oi1 = __shfl_xor(i1[i], off, 64);
            const float od2 = __shfl_xor(d2[i], off, 64);
            float loser;
            if (od1 < d1[i] || (od1 == d1[i] && oi1 < i1[i])) {
                loser = d1[i]; d1[i] = od1; i1[i] = oi1;
            } else {
                loser = od1;
            }
            d2[i] = fminf(fminf(d2[i], od2), loser);
        }
    }
    if (tx == 0) {
        #pragma unroll
        for (int i = 0; i < 4; ++i) {
            const int token = blk * 64 + ty * 4 + i;
            idx_ws[token]  = i1[i];
            idx_out[token] = (float)i1[i];
            if (d2[i] - d1[i] < TAU) {
                int slot = atomicAdd(refCount, 1);
                if (slot < REF_CAP) refList[slot] = token;
            }
        }
    }
}

// f64 exact re-scoring of near-tie tokens against all 1024 codes
__global__ __launch_bounds__(256) void refine_kernel(
    const float* __restrict__ z, const float* __restrict__ E,
    const int* __restrict__ refCount, const int* __restrict__ refList,
    int* __restrict__ idx_ws, float* __restrict__ idx_out)
{
    __shared__ double dists[KCB];
    const int lane = threadIdx.x & 63;
    const int wv   = threadIdx.x >> 6;
    int rc = *refCount; if (rc > REF_CAP) rc = REF_CAP;
    for (int r = blockIdx.x; r < rc; r += gridDim.x) {
        const int token = refList[r];
        double zr[8];
        const float* zp = z + (size_t)token * DIM + lane * 8;
        #pragma unroll
        for (int j = 0; j < 8; ++j) zr[j] = (double)zp[j];
        for (int c = wv; c < KCB; c += 4) {
            const float* ep = E + (size_t)c * DIM + lane * 8;
            double s = 0.0;
            #pragma unroll
            for (int j = 0; j < 8; ++j) { const double df = zr[j] - (double)ep[j]; s = fma(df, df, s); }
            for (int off = 32; off > 0; off >>= 1) s += __shfl_down(s, off, 64);
            if (lane == 0) dists[c] = s;
        }
        __syncthreads();
        if (threadIdx.x < 64) {
            double best = dists[lane]; int bi = lane;
            for (int c = lane + 64; c < KCB; c += 64) {
                const double dv = dists[c];
                if (dv < best) { best = dv; bi = c; }   // ascending c: strict < keeps lowest idx
            }
            for (int off = 32; off > 0; off >>= 1) {
                const double ob = __shfl_down(best, off, 64);
                const int    oi = __shfl_down(bi, off, 64);
                if (ob < best || (ob == best && oi < bi)) { best = ob; bi = oi; }
            }
            if (lane == 0) { idx_ws[token] = bi; idx_out[token] = (float)bi; }
        }
        __syncthreads();
    }
}

// quantized_st gather + histogram + embed_sum scatter (one wave per token)
__global__ __launch_bounds__(256) void gather_kernel(
    const float* __restrict__ z, const float* __restrict__ E,
    const int* __restrict__ idx_ws,
    float* __restrict__ out0, float* __restrict__ counts, float* __restrict__ esum)
{
    const int lane  = threadIdx.x & 63;
    const int wv    = threadIdx.x >> 6;
    const int token = blockIdx.x * 4 + wv;
    const int k = idx_ws[token];
    const float* zp = z + (size_t)token * DIM + lane * 8;
    const float* ep = E + (size_t)k * DIM + lane * 8;
    float* op = out0 + (size_t)token * DIM + lane * 8;
    float* sp = esum + (size_t)k * DIM + lane * 8;
    const float4 z0 = *(const float4*)zp, z1 = *(const float4*)(zp + 4);
    const float4 e0 = *(const float4*)ep, e1 = *(const float4*)(ep + 4);
    float4 o0, o1;
    o0.x = z0.x + (e0.x - z0.x); o0.y = z0.y + (e0.y - z0.y);
    o0.z = z0.z + (e0.z - z0.z); o0.w = z0.w + (e0.w - z0.w);
    o1.x = z1.x + (e1.x - z1.x); o1.y = z1.y + (e1.y - z1.y);
    o1.z = z1.z + (e1.z - z1.z); o1.w = z1.w + (e1.w - z1.w);
    *(float4*)op = o0; *(float4*)(op + 4) = o1;
    if (lane == 0) atomicAdd(counts + k, 1.0f);
    atomicAdd(sp + 0, z0.x); atomicAdd(sp + 1, z0.y);
    atomicAdd(sp + 2, z0.z); atomicAdd(sp + 3, z0.w);
    atomicAdd(sp + 4, z1.x); atomicAdd(sp + 5, z1.y);
    atomicAdd(sp + 6, z1.z); atomicAdd(sp + 7, z1.w);
}

__global__ __launch_bounds__(1024) void ema_cs_kernel(const float* __restrict__ cs,
    const float* __restrict__ counts, float* __restrict__ out3, float* __restrict__ n_ws)
{
    const int k = threadIdx.x;
    const float ncs = 0.99f * cs[k] + 0.01f * counts[k];
    out3[k] = ncs;
    float s = ncs;
    for (int off = 32; off > 0; off >>= 1) s += __shfl_down(s, off, 64);
    __shared__ float red[16];
    const int lane = k & 63, wv = k >> 6;
    if (lane == 0) red[wv] = s;
    __syncthreads();
    if (k == 0) {
        float t = 0.f;
        for (int i = 0; i < 16; ++i) t += red[i];
        n_ws[0] = t;
    }
}

__global__ __launch_bounds__(256) void ema_embed_kernel(const float* __restrict__ ea,
    const float* __restrict__ esum, const float* __restrict__ ncs_arr,
    const float* __restrict__ n_ws, float* __restrict__ out2, float* __restrict__ out4)
{
    const size_t i = (size_t)blockIdx.x * 256 + threadIdx.x;
    const int k = (int)(i >> 9);
    const float n = n_ws[0];
    const float ncs = ncs_arr[k];
    const float smoothed = (ncs + 1e-5f) / (n + 0.01024f) * n;
    const float nea = 0.99f * ea[i] + 0.01f * esum[i];
    out4[i] = nea;
    out2[i] = nea / smoothed;
}

extern "C" void kernel_launch(void* const* d_in, const int* in_sizes, int n_in,
                              void* d_out, int out_size, void* d_ws, size_t ws_size,
                              hipStream_t stream)
{
    const float* z  = (const float*)d_in[0];
    const float* E  = (const float*)d_in[1];
    const float* cs = (const float*)d_in[2];
    const float* ea = (const float*)d_in[3];

    float* out0 = (float*)d_out;                       // quantized_st [NTOK*DIM]
    float* out1 = out0 + (size_t)NTOK * DIM;           // indices (as f32) [NTOK]
    float* out2 = out1 + NTOK;                         // new_embedding [KCB*DIM]
    float* out3 = out2 + (size_t)KCB * DIM;            // new_cluster_size [KCB]
    float* out4 = out3 + KCB;                          // new_embed_avg [KCB*DIM]

    char* ws = (char*)d_ws;
    int*   idx_ws  = (int*)ws;
    float* counts  = (float*)(ws + 262144);
    float* esum    = (float*)(ws + 266240);
    float* esq     = (float*)(ws + 2363392);
    int*   refCnt  = (int*)(ws + 2367488);
    int*   refList = (int*)(ws + 2367504);
    float* n_ws    = (float*)(ws + 2400272);

    hipMemsetAsync(counts, 0, KCB * sizeof(float), stream);
    hipMemsetAsync(esum, 0, (size_t)KCB * DIM * sizeof(float), stream);
    hipMemsetAsync(refCnt, 0, sizeof(int), stream);

    esq_kernel<<<KCB / 4, 256, 0, stream>>>(E, esq);
    score_kernel<<<NTOK / 64, 256, 0, stream>>>(z, E, esq, idx_ws, out1, refCnt, refList);
    refine_kernel<<<256, 256, 0, stream>>>(z, E, refCnt, refList, idx_ws, out1);
    gather_kernel<<<NTOK / 4, 256, 0, stream>>>(z, E, idx_ws, out0, counts, esum);
    ema_cs_kernel<<<1, 1024, 0, stream>>>(cs, counts, out3, n_ws);
    ema_embed_kernel<<<(KCB * DIM) / 256, 256, 0, stream>>>(ea, esum, out3, n_ws, out2, out4);
}

// Round 2
// 1628.681 us; speedup vs baseline: 1.4889x; 1.4889x over previous
//
#include <hip/hip_runtime.h>
#include <cfloat>

#define NTOK 65536
#define DIM  512
#define KCB  1024
#define TAU  0.05f
#define REF_CAP 8192

// ---------------- ws layout (bytes) ----------------
// 0       : idx       int[NTOK]      262144
// 262144  : esq       f32[KCB]       4096
// 266240  : refCount  int (16B pad)
// 266256  : refList   int[REF_CAP]   32768
// 299024  : n         f32

__global__ __launch_bounds__(256) void esq_kernel(const float* __restrict__ E,
                                                  float* __restrict__ esq)
{
    const int lane = threadIdx.x & 63;
    const int wv   = threadIdx.x >> 6;
    const int k    = blockIdx.x * 4 + wv;
    const float* er = E + (size_t)k * DIM + lane * 8;
    float4 a = *(const float4*)er;
    float4 b = *(const float4*)(er + 4);
    float s = a.x*a.x + a.y*a.y + a.z*a.z + a.w*a.w
            + b.x*b.x + b.y*b.y + b.z*b.z + b.w*b.w;
    for (int off = 32; off > 0; off >>= 1) s += __shfl_down(s, off, 64);
    if (lane == 0) esq[k] = s;
}

// 64 tokens x 1024 codes per block; K staged in 64-wide chunks.
// dist' = ||e||^2 - 2 z.e  (per-token const ||z||^2 dropped: argmin-invariant)
__global__ __launch_bounds__(256) void score_kernel(
    const float* __restrict__ z, const float* __restrict__ E,
    const float* __restrict__ esq,
    int* __restrict__ idx_ws, float* __restrict__ idx_out,
    int* __restrict__ refCount, int* __restrict__ refList)
{
    __shared__ float zs[64][68];   // [token][d_local], pad 68 for bank spread
    __shared__ float es[64][64];   // [d_local][code_local] (transposed)
    const int tid = threadIdx.x;
    const int blk = blockIdx.x;
    const int ty = tid >> 4;       // 0..15 -> 4 tokens each
    const int tx = tid & 15;       // 0..15 -> 4 codes each
    const int rS = tid >> 2;       // staging row 0..63
    const int q0 = tid & 3;

    const float* zblk = z + (size_t)blk * 64 * DIM;

    float d1[4], d2[4]; int i1[4];
    #pragma unroll
    for (int i = 0; i < 4; ++i) { d1[i] = FLT_MAX; d2[i] = FLT_MAX; i1[i] = KCB; }

    for (int cc = 0; cc < 16; ++cc) {
        const int code0 = cc * 64;
        float acc[4][4] = {};
        for (int dk = 0; dk < 8; ++dk) {
            const int dbase = dk * 64;
            __syncthreads();
            #pragma unroll
            for (int m = 0; m < 4; ++m) {
                const int q = q0 + m * 4;
                float4 vz = *(const float4*)(zblk + (size_t)rS * DIM + dbase + q * 4);
                *(float4*)&zs[rS][q * 4] = vz;
                float4 ve = *(const float4*)(E + (size_t)(code0 + rS) * DIM + dbase + q * 4);
                es[q*4+0][rS] = ve.x;
                es[q*4+1][rS] = ve.y;
                es[q*4+2][rS] = ve.z;
                es[q*4+3][rS] = ve.w;
            }
            __syncthreads();
            #pragma unroll 4
            for (int dq = 0; dq < 16; ++dq) {
                float zr[4][4];
                #pragma unroll
                for (int i = 0; i < 4; ++i) {
                    float4 t = *(const float4*)&zs[ty*4+i][dq*4];
                    zr[i][0]=t.x; zr[i][1]=t.y; zr[i][2]=t.z; zr[i][3]=t.w;
                }
                #pragma unroll
                for (int dd = 0; dd < 4; ++dd) {
                    float4 ev = *(const float4*)&es[dq*4+dd][tx*4];
                    #pragma unroll
                    for (int i = 0; i < 4; ++i) {
                        const float zz = zr[i][dd];
                        acc[i][0] = fmaf(zz, ev.x, acc[i][0]);
                        acc[i][1] = fmaf(zz, ev.y, acc[i][1]);
                        acc[i][2] = fmaf(zz, ev.z, acc[i][2]);
                        acc[i][3] = fmaf(zz, ev.w, acc[i][3]);
                    }
                }
            }
        }
        #pragma unroll
        for (int j = 0; j < 4; ++j) {
            const int code = code0 + tx * 4 + j;
            const float ej = esq[code];
            #pragma unroll
            for (int i = 0; i < 4; ++i) {
                const float dist = ej - 2.0f * acc[i][j];
                if (dist < d1[i] || (dist == d1[i] && code < i1[i])) {
                    d2[i] = d1[i]; d1[i] = dist; i1[i] = code;
                } else {
                    d2[i] = fminf(d2[i], dist);
                }
            }
        }
    }
    // merge top-2 across the 16 tx lanes (low 4 lane bits)
    #pragma unroll
    for (int off = 1; off < 16; off <<= 1) {
        #pragma unroll
        for (int i = 0; i < 4; ++i) {
            const float od1 = __shfl_xor(d1[i], off, 64);
            const int   oi1 = __shfl_xor(i1[i], off, 64);
            const float od2 = __shfl_xor(d2[i], off, 64);
            float loser;
            if (od1 < d1[i] || (od1 == d1[i] && oi1 < i1[i])) {
                loser = d1[i]; d1[i] = od1; i1[i] = oi1;
            } else {
                loser = od1;
            }
            d2[i] = fminf(fminf(d2[i], od2), loser);
        }
    }
    if (tx == 0) {
        #pragma unroll
        for (int i = 0; i < 4; ++i) {
            const int token = blk * 64 + ty * 4 + i;
            idx_ws[token]  = i1[i];
            idx_out[token] = (float)i1[i];
            if (d2[i] - d1[i] < TAU) {
                int slot = atomicAdd(refCount, 1);
                if (slot < REF_CAP) refList[slot] = token;
            }
        }
    }
}

// f64 exact re-scoring of near-tie tokens against all 1024 codes
__global__ __launch_bounds__(256) void refine_kernel(
    const float* __restrict__ z, const float* __restrict__ E,
    const int* __restrict__ refCount, const int* __restrict__ refList,
    int* __restrict__ idx_ws, float* __restrict__ idx_out)
{
    __shared__ double dists[KCB];
    const int lane = threadIdx.x & 63;
    const int wv   = threadIdx.x >> 6;
    int rc = *refCount; if (rc > REF_CAP) rc = REF_CAP;
    for (int r = blockIdx.x; r < rc; r += gridDim.x) {
        const int token = refList[r];
        double zr[8];
        const float* zp = z + (size_t)token * DIM + lane * 8;
        #pragma unroll
        for (int j = 0; j < 8; ++j) zr[j] = (double)zp[j];
        for (int c = wv; c < KCB; c += 4) {
            const float* ep = E + (size_t)c * DIM + lane * 8;
            double s = 0.0;
            #pragma unroll
            for (int j = 0; j < 8; ++j) { const double df = zr[j] - (double)ep[j]; s = fma(df, df, s); }
            for (int off = 32; off > 0; off >>= 1) s += __shfl_down(s, off, 64);
            if (lane == 0) dists[c] = s;
        }
        __syncthreads();
        if (threadIdx.x < 64) {
            double best = dists[lane]; int bi = lane;
            for (int c = lane + 64; c < KCB; c += 64) {
                const double dv = dists[c];
                if (dv < best) { best = dv; bi = c; }   // ascending c: strict < keeps lowest idx
            }
            for (int off = 32; off > 0; off >>= 1) {
                const double ob = __shfl_down(best, off, 64);
                const int    oi = __shfl_down(bi, off, 64);
                if (ob < best || (ob == best && oi < bi)) { best = ob; bi = oi; }
            }
            if (lane == 0) { idx_ws[token] = bi; idx_out[token] = (float)bi; }
        }
        __syncthreads();
    }
}

// quantized_st: z + (e - z) == e to ~2 ulp -> pure codebook gather (write-only HBM)
__global__ __launch_bounds__(256) void out0_kernel(
    const float* __restrict__ E, const int* __restrict__ idx,
    float* __restrict__ out0)
{
    const int lane  = threadIdx.x & 63;
    const int wv    = threadIdx.x >> 6;
    const int token = blockIdx.x * 4 + wv;
    const int k = idx[token];
    const float* ep = E + (size_t)k * DIM + lane * 8;
    float* op = out0 + (size_t)token * DIM + lane * 8;
    const float4 e0 = *(const float4*)ep;
    const float4 e1 = *(const float4*)(ep + 4);
    *(float4*)op = e0;
    *(float4*)(op + 4) = e1;
}

// Code-major deterministic segment sum: block k scans idx (L2-resident),
// collects matching tokens in ascending order via ballot-rank, accumulates
// z rows cooperatively (thread owns dims 2*tid, 2*tid+1). No atomics.
__global__ __launch_bounds__(256) void code_sum_kernel(
    const float* __restrict__ z, const int* __restrict__ idx,
    const float* __restrict__ cs, const float* __restrict__ ea,
    float* __restrict__ out3, float* __restrict__ out4)
{
    const int k    = blockIdx.x;
    const int tid  = threadIdx.x;
    const int lane = tid & 63;
    const int wv   = tid >> 6;
    __shared__ unsigned long long wmask[4];
    __shared__ int toks[256];
    float2 acc = {0.f, 0.f};
    int total = 0;
    for (int t0 = 0; t0 < NTOK; t0 += 256) {
        const int p = (idx[t0 + tid] == k);
        const unsigned long long m = __ballot(p);
        if (lane == 0) wmask[wv] = m;
        __syncthreads();
        int nm = 0, base = 0;
        #pragma unroll
        for (int w = 0; w < 4; ++w) {
            const int c = __popcll(wmask[w]);
            if (w < wv) base += c;
            nm += c;
        }
        if (p) toks[base + __popcll(m & ((1ull << lane) - 1ull))] = t0 + tid;
        __syncthreads();
        for (int q = 0; q < nm; ++q) {
            const int t = toks[q];
            const float2 v = *(const float2*)(z + (size_t)t * DIM + tid * 2);
            acc.x += v.x; acc.y += v.y;
        }
        total += nm;
    }
    if (tid == 0) out3[k] = 0.99f * cs[k] + 0.01f * (float)total;
    const size_t o = (size_t)k * DIM + tid * 2;
    const float2 eav = *(const float2*)(ea + o);
    float2 o4;
    o4.x = 0.99f * eav.x + 0.01f * acc.x;
    o4.y = 0.99f * eav.y + 0.01f * acc.y;
    *(float2*)(out4 + o) = o4;
}

__global__ __launch_bounds__(1024) void n_kernel(const float* __restrict__ out3,
                                                 float* __restrict__ n_ws)
{
    const int k = threadIdx.x;
    float s = out3[k];
    for (int off = 32; off > 0; off >>= 1) s += __shfl_down(s, off, 64);
    __shared__ float red[16];
    const int lane = k & 63, wv = k >> 6;
    if (lane == 0) red[wv] = s;
    __syncthreads();
    if (k == 0) {
        float t = 0.f;
        for (int i = 0; i < 16; ++i) t += red[i];
        n_ws[0] = t;
    }
}

__global__ __launch_bounds__(256) void out2_kernel(const float* __restrict__ out4,
    const float* __restrict__ out3, const float* __restrict__ n_ws,
    float* __restrict__ out2)
{
    const size_t i = (size_t)blockIdx.x * 256 + threadIdx.x;
    const int k = (int)(i >> 9);
    const float n = n_ws[0];
    const float smoothed = (out3[k] + 1e-5f) / (n + 0.01024f) * n;
    out2[i] = out4[i] / smoothed;
}

extern "C" void kernel_launch(void* const* d_in, const int* in_sizes, int n_in,
                              void* d_out, int out_size, void* d_ws, size_t ws_size,
                              hipStream_t stream)
{
    const float* z  = (const float*)d_in[0];
    const float* E  = (const float*)d_in[1];
    const float* cs = (const float*)d_in[2];
    const float* ea = (const float*)d_in[3];

    float* out0 = (float*)d_out;                       // quantized_st [NTOK*DIM]
    float* out1 = out0 + (size_t)NTOK * DIM;           // indices (as f32) [NTOK]
    float* out2 = out1 + NTOK;                         // new_embedding [KCB*DIM]
    float* out3 = out2 + (size_t)KCB * DIM;            // new_cluster_size [KCB]
    float* out4 = out3 + KCB;                          // new_embed_avg [KCB*DIM]

    char* ws = (char*)d_ws;
    int*   idx_ws  = (int*)ws;
    float* esq     = (float*)(ws + 262144);
    int*   refCnt  = (int*)(ws + 266240);
    int*   refList = (int*)(ws + 266256);
    float* n_ws    = (float*)(ws + 299024);

    hipMemsetAsync(refCnt, 0, sizeof(int), stream);

    esq_kernel<<<KCB / 4, 256, 0, stream>>>(E, esq);
    score_kernel<<<NTOK / 64, 256, 0, stream>>>(z, E, esq, idx_ws, out1, refCnt, refList);
    refine_kernel<<<256, 256, 0, stream>>>(z, E, refCnt, refList, idx_ws, out1);
    out0_kernel<<<NTOK / 4, 256, 0, stream>>>(E, idx_ws, out0);
    code_sum_kernel<<<KCB, 256, 0, stream>>>(z, idx_ws, cs, ea, out3, out4);
    n_kernel<<<1, 1024, 0, stream>>>(out3, n_ws);
    out2_kernel<<<(KCB * DIM) / 256, 256, 0, stream>>>(out4, out3, n_ws, out2);
}

// Round 3
// 879.529 us; speedup vs baseline: 2.7571x; 1.8518x over previous
//
#include <hip/hip_runtime.h>
#include <cfloat>

#define NTOK 65536
#define DIM  512
#define KCB  1024
#define TAU  0.05f
#define REF_CAP 8192

typedef unsigned short u16;
typedef __attribute__((ext_vector_type(8))) short short8;
typedef __attribute__((ext_vector_type(4))) float f32x4;

// ---------------- ws layout (bytes) ----------------
// 0       : idx       int[NTOK]        262144
// 262144  : esq       f32[KCB]         4096
// 266240  : refCount  int (16B pad)
// 266256  : refList   int[REF_CAP]     32768
// 299024  : n         f32
// 299072  : E_hi      u16[KCB*DIM]     1048576
// 1347648 : E_lo      u16[KCB*DIM]     1048576   (end 2396224)

__device__ __forceinline__ u16 f2bf(float f) {
    unsigned int u = __float_as_uint(f);
    u += 0x7FFF + ((u >> 16) & 1);
    return (u16)(u >> 16);
}
__device__ __forceinline__ float bf2f(u16 h) {
    return __uint_as_float(((unsigned int)h) << 16);
}

__global__ __launch_bounds__(256) void esq_kernel(const float* __restrict__ E,
                                                  float* __restrict__ esq)
{
    const int lane = threadIdx.x & 63;
    const int wv   = threadIdx.x >> 6;
    const int k    = blockIdx.x * 4 + wv;
    const float* er = E + (size_t)k * DIM + lane * 8;
    float4 a = *(const float4*)er;
    float4 b = *(const float4*)(er + 4);
    float s = a.x*a.x + a.y*a.y + a.z*a.z + a.w*a.w
            + b.x*b.x + b.y*b.y + b.z*b.z + b.w*b.w;
    for (int off = 32; off > 0; off >>= 1) s += __shfl_down(s, off, 64);
    if (lane == 0) esq[k] = s;
}

// Decompose E into bf16 hi + bf16 residual lo (row-major [KCB][DIM])
__global__ __launch_bounds__(256) void ehilo_kernel(const float* __restrict__ E,
                                                    u16* __restrict__ Ehi,
                                                    u16* __restrict__ Elo)
{
    const size_t i = (size_t)blockIdx.x * 256 + threadIdx.x;   // pair index
    const float2 v = *(const float2*)(E + i * 2);
    const u16 h0 = f2bf(v.x), h1 = f2bf(v.y);
    const u16 l0 = f2bf(v.x - bf2f(h0)), l1 = f2bf(v.y - bf2f(h1));
    ((unsigned int*)Ehi)[i] = ((unsigned int)h1 << 16) | h0;
    ((unsigned int*)Elo)[i] = ((unsigned int)l1 << 16) | l0;
}

// MFMA split-bf16 scoring: 64 tokens/block (16/wave, K=512 in regs),
// 64 chunks of 16 codes staged in swizzled LDS.
// dist' = ||e||^2 - 2 z.e ; per-lane top-2, one cross-lane merge at end.
__global__ __launch_bounds__(256, 2) void score_kernel(
    const float* __restrict__ z,
    const u16* __restrict__ Ehi, const u16* __restrict__ Elo,
    const float* __restrict__ esq,
    int* __restrict__ idx_ws, float* __restrict__ idx_out,
    int* __restrict__ refCount, int* __restrict__ refList)
{
    __shared__ u16 ehi_t[16 * 512];     // 16 KB, slot-swizzled rows
    __shared__ u16 elo_t[16 * 512];     // 16 KB
    __shared__ float esq_lds[KCB];      // 4 KB

    const int tid  = threadIdx.x;
    const int lane = tid & 63;
    const int wv   = tid >> 6;
    const int blk  = blockIdx.x;
    const int tokbase = blk * 64 + wv * 16;

    for (int i = tid; i < KCB; i += 256) esq_lds[i] = esq[i];

    // ---- A fragments: 16 tokens x K=512, bf16 hi/lo, in registers ----
    // A[row][k]: row = lane&15, k = kc*32 + (lane>>4)*8 + j
    short8 zh[16], zl[16];
    {
        const float* zr = z + (size_t)(tokbase + (lane & 15)) * DIM + ((lane >> 4) << 3);
        #pragma unroll
        for (int kc = 0; kc < 16; ++kc) {
            float4 a = *(const float4*)(zr + kc * 32);
            float4 b = *(const float4*)(zr + kc * 32 + 4);
            float v[8] = {a.x, a.y, a.z, a.w, b.x, b.y, b.z, b.w};
            short8 h, l;
            #pragma unroll
            for (int j = 0; j < 8; ++j) {
                const u16 hb = f2bf(v[j]);
                h[j] = (short)hb;
                l[j] = (short)f2bf(v[j] - bf2f(hb));
            }
            zh[kc] = h; zl[kc] = l;
        }
    }

    float d1[4], d2[4]; int i1[4];
    #pragma unroll
    for (int r = 0; r < 4; ++r) { d1[r] = FLT_MAX; d2[r] = FLT_MAX; i1[r] = KCB; }

    for (int ch = 0; ch < 64; ++ch) {
        __syncthreads();   // previous chunk's reads done before overwrite
        // stage 16-code tile; wave wv stages rows 4wv..4wv+3 (hi and lo).
        // LDS row linear in lane (slot=lane); global src slot = lane ^ (c&7)
        // so a read at slot s^(c&7) yields logical slot s (both-sides swizzle).
        #pragma unroll
        for (int i = 0; i < 4; ++i) {
            const int c = (wv << 2) + i;
            const size_t grow = (size_t)((ch << 4) + c) * 512;
            const int soff = (lane ^ (c & 7)) << 3;   // u16 units (16B granules)
            __builtin_amdgcn_global_load_lds(
                (const __attribute__((address_space(1))) void*)(Ehi + grow + soff),
                (__attribute__((address_space(3))) void*)&ehi_t[c * 512], 16, 0, 0);
            __builtin_amdgcn_global_load_lds(
                (const __attribute__((address_space(1))) void*)(Elo + grow + soff),
                (__attribute__((address_space(3))) void*)&elo_t[c * 512], 16, 0, 0);
        }
        __syncthreads();   // drains vmcnt: tile ready

        f32x4 acc = {0.f, 0.f, 0.f, 0.f};
        #pragma unroll
        for (int kc = 0; kc < 16; ++kc) {
            // B[k][col]: col = lane&15 (code row in tile), slot = kc*4 + (lane>>4)
            const int slot = (kc << 2) + (lane >> 4);
            const int base = (lane & 15) * 512 + ((slot ^ (lane & 7)) << 3);
            const short8 eh = *(const short8*)&ehi_t[base];
            const short8 el = *(const short8*)&elo_t[base];
            acc = __builtin_amdgcn_mfma_f32_16x16x32_bf16(zh[kc], eh, acc, 0, 0, 0);
            acc = __builtin_amdgcn_mfma_f32_16x16x32_bf16(zh[kc], el, acc, 0, 0, 0);
            acc = __builtin_amdgcn_mfma_f32_16x16x32_bf16(zl[kc], eh, acc, 0, 0, 0);
        }

        // C/D layout: col = lane&15 -> code, row = (lane>>4)*4 + r -> token
        const int code = (ch << 4) + (lane & 15);
        const float ej = esq_lds[code];
        #pragma unroll
        for (int r = 0; r < 4; ++r) {
            const float dist = fmaf(-2.0f, acc[r], ej);
            if (dist < d1[r]) { d2[r] = d1[r]; d1[r] = dist; i1[r] = code; }
            else              { d2[r] = fminf(d2[r], dist); }
        }
    }

    // merge top-2 across the 16 code-lanes (low 4 lane bits)
    #pragma unroll
    for (int off = 1; off < 16; off <<= 1) {
        #pragma unroll
        for (int r = 0; r < 4; ++r) {
            const float od1 = __shfl_xor(d1[r], off, 64);
            const int   oi1 = __shfl_xor(i1[r], off, 64);
            const float od2 = __shfl_xor(d2[r], off, 64);
            float loser;
            if (od1 < d1[r] || (od1 == d1[r] && oi1 < i1[r])) {
                loser = d1[r]; d1[r] = od1; i1[r] = oi1;
            } else {
                loser = od1;
            }
            d2[r] = fminf(fminf(d2[r], od2), loser);
        }
    }
    if ((lane & 15) == 0) {
        #pragma unroll
        for (int r = 0; r < 4; ++r) {
            const int token = tokbase + ((lane >> 4) << 2) + r;
            idx_ws[token]  = i1[r];
            idx_out[token] = (float)i1[r];
            if (d2[r] - d1[r] < TAU) {
                int slot = atomicAdd(refCount, 1);
                if (slot < REF_CAP) refList[slot] = token;
            }
        }
    }
}

// f64 exact re-scoring of near-tie tokens against all 1024 codes
__global__ __launch_bounds__(256) void refine_kernel(
    const float* __restrict__ z, const float* __restrict__ E,
    const int* __restrict__ refCount, const int* __restrict__ refList,
    int* __restrict__ idx_ws, float* __restrict__ idx_out)
{
    __shared__ double dists[KCB];
    const int lane = threadIdx.x & 63;
    const int wv   = threadIdx.x >> 6;
    int rc = *refCount; if (rc > REF_CAP) rc = REF_CAP;
    for (int r = blockIdx.x; r < rc; r += gridDim.x) {
        const int token = refList[r];
        double zr[8];
        const float* zp = z + (size_t)token * DIM + lane * 8;
        #pragma unroll
        for (int j = 0; j < 8; ++j) zr[j] = (double)zp[j];
        for (int c = wv; c < KCB; c += 4) {
            const float* ep = E + (size_t)c * DIM + lane * 8;
            double s = 0.0;
            #pragma unroll
            for (int j = 0; j < 8; ++j) { const double df = zr[j] - (double)ep[j]; s = fma(df, df, s); }
            for (int off = 32; off > 0; off >>= 1) s += __shfl_down(s, off, 64);
            if (lane == 0) dists[c] = s;
        }
        __syncthreads();
        if (threadIdx.x < 64) {
            double best = dists[lane]; int bi = lane;
            for (int c = lane + 64; c < KCB; c += 64) {
                const double dv = dists[c];
                if (dv < best) { best = dv; bi = c; }
            }
            for (int off = 32; off > 0; off >>= 1) {
                const double ob = __shfl_down(best, off, 64);
                const int    oi = __shfl_down(bi, off, 64);
                if (ob < best || (ob == best && oi < bi)) { best = ob; bi = oi; }
            }
            if (lane == 0) { idx_ws[token] = bi; idx_out[token] = (float)bi; }
        }
        __syncthreads();
    }
}

// quantized_st: z + (e - z) == e -> pure codebook gather
__global__ __launch_bounds__(256) void out0_kernel(
    const float* __restrict__ E, const int* __restrict__ idx,
    float* __restrict__ out0)
{
    const int lane  = threadIdx.x & 63;
    const int wv    = threadIdx.x >> 6;
    const int token = blockIdx.x * 4 + wv;
    const int k = idx[token];
    const float* ep = E + (size_t)k * DIM + lane * 8;
    float* op = out0 + (size_t)token * DIM + lane * 8;
    const float4 e0 = *(const float4*)ep;
    const float4 e1 = *(const float4*)(ep + 4);
    *(float4*)op = e0;
    *(float4*)(op + 4) = e1;
}

// Code-major deterministic segment sum (no atomics)
__global__ __launch_bounds__(256) void code_sum_kernel(
    const float* __restrict__ z, const int* __restrict__ idx,
    const float* __restrict__ cs, const float* __restrict__ ea,
    float* __restrict__ out3, float* __restrict__ out4)
{
    const int k    = blockIdx.x;
    const int tid  = threadIdx.x;
    const int lane = tid & 63;
    const int wv   = tid >> 6;
    __shared__ unsigned long long wmask[4];
    __shared__ int toks[256];
    float2 acc = {0.f, 0.f};
    int total = 0;
    for (int t0 = 0; t0 < NTOK; t0 += 256) {
        const int p = (idx[t0 + tid] == k);
        const unsigned long long m = __ballot(p);
        if (lane == 0) wmask[wv] = m;
        __syncthreads();
        int nm = 0, base = 0;
        #pragma unroll
        for (int w = 0; w < 4; ++w) {
            const int c = __popcll(wmask[w]);
            if (w < wv) base += c;
            nm += c;
        }
        if (p) toks[base + __popcll(m & ((1ull << lane) - 1ull))] = t0 + tid;
        __syncthreads();
        for (int q = 0; q < nm; ++q) {
            const int t = toks[q];
            const float2 v = *(const float2*)(z + (size_t)t * DIM + tid * 2);
            acc.x += v.x; acc.y += v.y;
        }
        total += nm;
    }
    if (tid == 0) out3[k] = 0.99f * cs[k] + 0.01f * (float)total;
    const size_t o = (size_t)k * DIM + tid * 2;
    const float2 eav = *(const float2*)(ea + o);
    float2 o4;
    o4.x = 0.99f * eav.x + 0.01f * acc.x;
    o4.y = 0.99f * eav.y + 0.01f * acc.y;
    *(float2*)(out4 + o) = o4;
}

__global__ __launch_bounds__(1024) void n_kernel(const float* __restrict__ out3,
                                                 float* __restrict__ n_ws)
{
    const int k = threadIdx.x;
    float s = out3[k];
    for (int off = 32; off > 0; off >>= 1) s += __shfl_down(s, off, 64);
    __shared__ float red[16];
    const int lane = k & 63, wv = k >> 6;
    if (lane == 0) red[wv] = s;
    __syncthreads();
    if (k == 0) {
        float t = 0.f;
        for (int i = 0; i < 16; ++i) t += red[i];
        n_ws[0] = t;
    }
}

__global__ __launch_bounds__(256) void out2_kernel(const float* __restrict__ out4,
    const float* __restrict__ out3, const float* __restrict__ n_ws,
    float* __restrict__ out2)
{
    const size_t i = (size_t)blockIdx.x * 256 + threadIdx.x;
    const int k = (int)(i >> 9);
    const float n = n_ws[0];
    const float smoothed = (out3[k] + 1e-5f) / (n + 0.01024f) * n;
    out2[i] = out4[i] / smoothed;
}

extern "C" void kernel_launch(void* const* d_in, const int* in_sizes, int n_in,
                              void* d_out, int out_size, void* d_ws, size_t ws_size,
                              hipStream_t stream)
{
    const float* z  = (const float*)d_in[0];
    const float* E  = (const float*)d_in[1];
    const float* cs = (const float*)d_in[2];
    const float* ea = (const float*)d_in[3];

    float* out0 = (float*)d_out;                       // quantized_st [NTOK*DIM]
    float* out1 = out0 + (size_t)NTOK * DIM;           // indices (as f32) [NTOK]
    float* out2 = out1 + NTOK;                         // new_embedding [KCB*DIM]
    float* out3 = out2 + (size_t)KCB * DIM;            // new_cluster_size [KCB]
    float* out4 = out3 + KCB;                          // new_embed_avg [KCB*DIM]

    char* ws = (char*)d_ws;
    int*   idx_ws  = (int*)ws;
    float* esq     = (float*)(ws + 262144);
    int*   refCnt  = (int*)(ws + 266240);
    int*   refList = (int*)(ws + 266256);
    float* n_ws    = (float*)(ws + 299024);
    u16*   Ehi     = (u16*)(ws + 299072);
    u16*   Elo     = (u16*)(ws + 1347648);

    hipMemsetAsync(refCnt, 0, sizeof(int), stream);

    esq_kernel<<<KCB / 4, 256, 0, stream>>>(E, esq);
    ehilo_kernel<<<(KCB * DIM / 2) / 256, 256, 0, stream>>>(E, Ehi, Elo);
    score_kernel<<<NTOK / 64, 256, 0, stream>>>(z, Ehi, Elo, esq, idx_ws, out1, refCnt, refList);
    refine_kernel<<<256, 256, 0, stream>>>(z, E, refCnt, refList, idx_ws, out1);
    out0_kernel<<<NTOK / 4, 256, 0, stream>>>(E, idx_ws, out0);
    code_sum_kernel<<<KCB, 256, 0, stream>>>(z, idx_ws, cs, ea, out3, out4);
    n_kernel<<<1, 1024, 0, stream>>>(out3, n_ws);
    out2_kernel<<<(KCB * DIM) / 256, 256, 0, stream>>>(out4, out3, n_ws, out2);
}

// Round 4
// 642.821 us; speedup vs baseline: 3.7724x; 1.3682x over previous
//
#include <hip/hip_runtime.h>
#include <cfloat>

#define NTOK 65536
#define DIM  512
#define KCB  1024
#define TAU  0.05f
#define REF_CAP 8192

typedef unsigned short u16;
typedef __attribute__((ext_vector_type(8))) short short8;
typedef __attribute__((ext_vector_type(4))) float f32x4;

// ---------------- ws layout (bytes) ----------------
// 0       : idx       int[NTOK]        262144
// 262144  : esq       f32[KCB]         4096
// 266240  : refCount  int (16B pad)
// 266256  : refList   int[REF_CAP]     32768
// 299024  : n         f32
// 299072  : E_hi      u16[KCB*DIM]     1048576
// 1347648 : E_lo      u16[KCB*DIM]     1048576   (end 2396224)

__device__ __forceinline__ u16 f2bf(float f) {
    unsigned int u = __float_as_uint(f);
    u += 0x7FFF + ((u >> 16) & 1);
    return (u16)(u >> 16);
}
__device__ __forceinline__ float bf2f(u16 h) {
    return __uint_as_float(((unsigned int)h) << 16);
}

__global__ __launch_bounds__(256) void esq_kernel(const float* __restrict__ E,
                                                  float* __restrict__ esq)
{
    const int lane = threadIdx.x & 63;
    const int wv   = threadIdx.x >> 6;
    const int k    = blockIdx.x * 4 + wv;
    const float* er = E + (size_t)k * DIM + lane * 8;
    float4 a = *(const float4*)er;
    float4 b = *(const float4*)(er + 4);
    float s = a.x*a.x + a.y*a.y + a.z*a.z + a.w*a.w
            + b.x*b.x + b.y*b.y + b.z*b.z + b.w*b.w;
    for (int off = 32; off > 0; off >>= 1) s += __shfl_down(s, off, 64);
    if (lane == 0) esq[k] = s;
}

// Decompose E into bf16 hi + bf16 residual lo (row-major [KCB][DIM])
__global__ __launch_bounds__(256) void ehilo_kernel(const float* __restrict__ E,
                                                    u16* __restrict__ Ehi,
                                                    u16* __restrict__ Elo)
{
    const size_t i = (size_t)blockIdx.x * 256 + threadIdx.x;   // pair index
    const float2 v = *(const float2*)(E + i * 2);
    const u16 h0 = f2bf(v.x), h1 = f2bf(v.y);
    const u16 l0 = f2bf(v.x - bf2f(h0)), l1 = f2bf(v.y - bf2f(h1));
    ((unsigned int*)Ehi)[i] = ((unsigned int)h1 << 16) | h0;
    ((unsigned int*)Elo)[i] = ((unsigned int)l1 << 16) | l0;
}

// MFMA split-bf16 scoring: 64 tokens/block (16/wave, K=512 in regs),
// 64 chunks of 16 codes staged in swizzled LDS.
// dist' = ||e||^2 - 2 z.e ; per-lane top-2, one cross-lane merge at end.
__global__ __launch_bounds__(256, 2) void score_kernel(
    const float* __restrict__ z,
    const u16* __restrict__ Ehi, const u16* __restrict__ Elo,
    const float* __restrict__ esq,
    int* __restrict__ idx_ws, float* __restrict__ idx_out,
    int* __restrict__ refCount, int* __restrict__ refList)
{
    __shared__ u16 ehi_t[16 * 512];     // 16 KB, slot-swizzled rows
    __shared__ u16 elo_t[16 * 512];     // 16 KB
    __shared__ float esq_lds[KCB];      // 4 KB

    const int tid  = threadIdx.x;
    const int lane = tid & 63;
    const int wv   = tid >> 6;
    const int blk  = blockIdx.x;
    const int tokbase = blk * 64 + wv * 16;

    for (int i = tid; i < KCB; i += 256) esq_lds[i] = esq[i];

    // ---- A fragments: 16 tokens x K=512, bf16 hi/lo, in registers ----
    // A[row][k]: row = lane&15, k = kc*32 + (lane>>4)*8 + j
    short8 zh[16], zl[16];
    {
        const float* zr = z + (size_t)(tokbase + (lane & 15)) * DIM + ((lane >> 4) << 3);
        #pragma unroll
        for (int kc = 0; kc < 16; ++kc) {
            float4 a = *(const float4*)(zr + kc * 32);
            float4 b = *(const float4*)(zr + kc * 32 + 4);
            float v[8] = {a.x, a.y, a.z, a.w, b.x, b.y, b.z, b.w};
            short8 h, l;
            #pragma unroll
            for (int j = 0; j < 8; ++j) {
                const u16 hb = f2bf(v[j]);
                h[j] = (short)hb;
                l[j] = (short)f2bf(v[j] - bf2f(hb));
            }
            zh[kc] = h; zl[kc] = l;
        }
    }

    float d1[4], d2[4]; int i1[4];
    #pragma unroll
    for (int r = 0; r < 4; ++r) { d1[r] = FLT_MAX; d2[r] = FLT_MAX; i1[r] = KCB; }

    for (int ch = 0; ch < 64; ++ch) {
        __syncthreads();   // previous chunk's reads done before overwrite
        // stage 16-code tile; wave wv stages rows 4wv..4wv+3 (hi and lo).
        // LDS row linear in lane (slot=lane); global src slot = lane ^ (c&7)
        // so a read at slot s^(c&7) yields logical slot s (both-sides swizzle).
        #pragma unroll
        for (int i = 0; i < 4; ++i) {
            const int c = (wv << 2) + i;
            const size_t grow = (size_t)((ch << 4) + c) * 512;
            const int soff = (lane ^ (c & 7)) << 3;   // u16 units (16B granules)
            __builtin_amdgcn_global_load_lds(
                (const __attribute__((address_space(1))) void*)(Ehi + grow + soff),
                (__attribute__((address_space(3))) void*)&ehi_t[c * 512], 16, 0, 0);
            __builtin_amdgcn_global_load_lds(
                (const __attribute__((address_space(1))) void*)(Elo + grow + soff),
                (__attribute__((address_space(3))) void*)&elo_t[c * 512], 16, 0, 0);
        }
        __syncthreads();   // drains vmcnt: tile ready

        f32x4 acc = {0.f, 0.f, 0.f, 0.f};
        #pragma unroll
        for (int kc = 0; kc < 16; ++kc) {
            // B[k][col]: col = lane&15 (code row in tile), slot = kc*4 + (lane>>4)
            const int slot = (kc << 2) + (lane >> 4);
            const int base = (lane & 15) * 512 + ((slot ^ (lane & 7)) << 3);
            const short8 eh = *(const short8*)&ehi_t[base];
            const short8 el = *(const short8*)&elo_t[base];
            acc = __builtin_amdgcn_mfma_f32_16x16x32_bf16(zh[kc], eh, acc, 0, 0, 0);
            acc = __builtin_amdgcn_mfma_f32_16x16x32_bf16(zh[kc], el, acc, 0, 0, 0);
            acc = __builtin_amdgcn_mfma_f32_16x16x32_bf16(zl[kc], eh, acc, 0, 0, 0);
        }

        // C/D layout: col = lane&15 -> code, row = (lane>>4)*4 + r -> token
        const int code = (ch << 4) + (lane & 15);
        const float ej = esq_lds[code];
        #pragma unroll
        for (int r = 0; r < 4; ++r) {
            const float dist = fmaf(-2.0f, acc[r], ej);
            if (dist < d1[r]) { d2[r] = d1[r]; d1[r] = dist; i1[r] = code; }
            else              { d2[r] = fminf(d2[r], dist); }
        }
    }

    // merge top-2 across the 16 code-lanes (low 4 lane bits)
    #pragma unroll
    for (int off = 1; off < 16; off <<= 1) {
        #pragma unroll
        for (int r = 0; r < 4; ++r) {
            const float od1 = __shfl_xor(d1[r], off, 64);
            const int   oi1 = __shfl_xor(i1[r], off, 64);
            const float od2 = __shfl_xor(d2[r], off, 64);
            float loser;
            if (od1 < d1[r] || (od1 == d1[r] && oi1 < i1[r])) {
                loser = d1[r]; d1[r] = od1; i1[r] = oi1;
            } else {
                loser = od1;
            }
            d2[r] = fminf(fminf(d2[r], od2), loser);
        }
    }
    if ((lane & 15) == 0) {
        #pragma unroll
        for (int r = 0; r < 4; ++r) {
            const int token = tokbase + ((lane >> 4) << 2) + r;
            idx_ws[token]  = i1[r];
            idx_out[token] = (float)i1[r];
            if (d2[r] - d1[r] < TAU) {
                int slot = atomicAdd(refCount, 1);
                if (slot < REF_CAP) refList[slot] = token;
            }
        }
    }
}

// f64 exact re-scoring of near-tie tokens against all 1024 codes
__global__ __launch_bounds__(256) void refine_kernel(
    const float* __restrict__ z, const float* __restrict__ E,
    const int* __restrict__ refCount, const int* __restrict__ refList,
    int* __restrict__ idx_ws, float* __restrict__ idx_out)
{
    __shared__ double dists[KCB];
    const int lane = threadIdx.x & 63;
    const int wv   = threadIdx.x >> 6;
    int rc = *refCount; if (rc > REF_CAP) rc = REF_CAP;
    for (int r = blockIdx.x; r < rc; r += gridDim.x) {
        const int token = refList[r];
        double zr[8];
        const float* zp = z + (size_t)token * DIM + lane * 8;
        #pragma unroll
        for (int j = 0; j < 8; ++j) zr[j] = (double)zp[j];
        for (int c = wv; c < KCB; c += 4) {
            const float* ep = E + (size_t)c * DIM + lane * 8;
            double s = 0.0;
            #pragma unroll
            for (int j = 0; j < 8; ++j) { const double df = zr[j] - (double)ep[j]; s = fma(df, df, s); }
            for (int off = 32; off > 0; off >>= 1) s += __shfl_down(s, off, 64);
            if (lane == 0) dists[c] = s;
        }
        __syncthreads();
        if (threadIdx.x < 64) {
            double best = dists[lane]; int bi = lane;
            for (int c = lane + 64; c < KCB; c += 64) {
                const double dv = dists[c];
                if (dv < best) { best = dv; bi = c; }
            }
            for (int off = 32; off > 0; off >>= 1) {
                const double ob = __shfl_down(best, off, 64);
                const int    oi = __shfl_down(bi, off, 64);
                if (ob < best || (ob == best && oi < bi)) { best = ob; bi = oi; }
            }
            if (lane == 0) { idx_ws[token] = bi; idx_out[token] = (float)bi; }
        }
        __syncthreads();
    }
}

// quantized_st: z + (e - z) == e -> pure codebook gather
__global__ __launch_bounds__(256) void out0_kernel(
    const float* __restrict__ E, const int* __restrict__ idx,
    float* __restrict__ out0)
{
    const int lane  = threadIdx.x & 63;
    const int wv    = threadIdx.x >> 6;
    const int token = blockIdx.x * 4 + wv;
    const int k = idx[token];
    const float* ep = E + (size_t)k * DIM + lane * 8;
    float* op = out0 + (size_t)token * DIM + lane * 8;
    const float4 e0 = *(const float4*)ep;
    const float4 e1 = *(const float4*)(ep + 4);
    *(float4*)op = e0;
    *(float4*)(op + 4) = e1;
}

// Code-major deterministic segment sum, wave-autonomous scan (no barriers
// in the main loop). Wave wv scans a contiguous quarter of idx; matched
// tokens (wave-uniform mask) trigger a cooperative z-row accumulate
// (lane owns dims lane*8..lane*8+7). One final LDS reduction, fixed order.
__global__ __launch_bounds__(256) void code_sum_kernel(
    const float* __restrict__ z, const int* __restrict__ idx,
    const float* __restrict__ cs, const float* __restrict__ ea,
    float* __restrict__ out3, float* __restrict__ out4)
{
    const int k    = blockIdx.x;
    const int tid  = threadIdx.x;
    const int lane = tid & 63;
    const int wv   = tid >> 6;
    __shared__ float part[4][512];   // 8 KB
    __shared__ int   pcnt[4];

    float acc[8] = {0.f,0.f,0.f,0.f,0.f,0.f,0.f,0.f};
    int cnt = 0;
    const int base0 = wv * (NTOK / 4);

    for (int c = 0; c < NTOK / 4; c += 256) {
        const int b = base0 + c + lane;
        const int v0 = idx[b];
        const int v1 = idx[b + 64];
        const int v2 = idx[b + 128];
        const int v3 = idx[b + 192];
        unsigned long long m[4];
        m[0] = __ballot(v0 == k);
        m[1] = __ballot(v1 == k);
        m[2] = __ballot(v2 == k);
        m[3] = __ballot(v3 == k);
        #pragma unroll
        for (int u = 0; u < 4; ++u) {
            unsigned long long mm = m[u];
            cnt += __popcll(mm);
            while (mm) {
                const int bit = __ffsll((unsigned long long)mm) - 1;
                mm &= mm - 1;
                const int t = base0 + c + u * 64 + bit;
                const float* zp = z + (size_t)t * DIM + lane * 8;
                const float4 a  = *(const float4*)zp;
                const float4 bb = *(const float4*)(zp + 4);
                acc[0] += a.x;  acc[1] += a.y;  acc[2] += a.z;  acc[3] += a.w;
                acc[4] += bb.x; acc[5] += bb.y; acc[6] += bb.z; acc[7] += bb.w;
            }
        }
    }

    #pragma unroll
    for (int j = 0; j < 8; ++j) part[wv][lane * 8 + j] = acc[j];
    if (lane == 0) pcnt[wv] = cnt;
    __syncthreads();

    if (tid == 0) {
        const int total = pcnt[0] + pcnt[1] + pcnt[2] + pcnt[3];
        out3[k] = 0.99f * cs[k] + 0.01f * (float)total;
    }
    const int d = tid * 2;
    const float sx = part[0][d]     + part[1][d]     + part[2][d]     + part[3][d];
    const float sy = part[0][d + 1] + part[1][d + 1] + part[2][d + 1] + part[3][d + 1];
    const size_t o = (size_t)k * DIM + d;
    const float2 eav = *(const float2*)(ea + o);
    float2 o4;
    o4.x = 0.99f * eav.x + 0.01f * sx;
    o4.y = 0.99f * eav.y + 0.01f * sy;
    *(float2*)(out4 + o) = o4;
}

__global__ __launch_bounds__(1024) void n_kernel(const float* __restrict__ out3,
                                                 float* __restrict__ n_ws)
{
    const int k = threadIdx.x;
    float s = out3[k];
    for (int off = 32; off > 0; off >>= 1) s += __shfl_down(s, off, 64);
    __shared__ float red[16];
    const int lane = k & 63, wv = k >> 6;
    if (lane == 0) red[wv] = s;
    __syncthreads();
    if (k == 0) {
        float t = 0.f;
        for (int i = 0; i < 16; ++i) t += red[i];
        n_ws[0] = t;
    }
}

__global__ __launch_bounds__(256) void out2_kernel(const float* __restrict__ out4,
    const float* __restrict__ out3, const float* __restrict__ n_ws,
    float* __restrict__ out2)
{
    const size_t i = (size_t)blockIdx.x * 256 + threadIdx.x;
    const int k = (int)(i >> 9);
    const float n = n_ws[0];
    const float smoothed = (out3[k] + 1e-5f) / (n + 0.01024f) * n;
    out2[i] = out4[i] / smoothed;
}

extern "C" void kernel_launch(void* const* d_in, const int* in_sizes, int n_in,
                              void* d_out, int out_size, void* d_ws, size_t ws_size,
                              hipStream_t stream)
{
    const float* z  = (const float*)d_in[0];
    const float* E  = (const float*)d_in[1];
    const float* cs = (const float*)d_in[2];
    const float* ea = (const float*)d_in[3];

    float* out0 = (float*)d_out;                       // quantized_st [NTOK*DIM]
    float* out1 = out0 + (size_t)NTOK * DIM;           // indices (as f32) [NTOK]
    float* out2 = out1 + NTOK;                         // new_embedding [KCB*DIM]
    float* out3 = out2 + (size_t)KCB * DIM;            // new_cluster_size [KCB]
    float* out4 = out3 + KCB;                          // new_embed_avg [KCB*DIM]

    char* ws = (char*)d_ws;
    int*   idx_ws  = (int*)ws;
    float* esq     = (float*)(ws + 262144);
    int*   refCnt  = (int*)(ws + 266240);
    int*   refList = (int*)(ws + 266256);
    float* n_ws    = (float*)(ws + 299024);
    u16*   Ehi     = (u16*)(ws + 299072);
    u16*   Elo     = (u16*)(ws + 1347648);

    hipMemsetAsync(refCnt, 0, sizeof(int), stream);

    esq_kernel<<<KCB / 4, 256, 0, stream>>>(E, esq);
    ehilo_kernel<<<(KCB * DIM / 2) / 256, 256, 0, stream>>>(E, Ehi, Elo);
    score_kernel<<<NTOK / 64, 256, 0, stream>>>(z, Ehi, Elo, esq, idx_ws, out1, refCnt, refList);
    refine_kernel<<<256, 256, 0, stream>>>(z, E, refCnt, refList, idx_ws, out1);
    out0_kernel<<<NTOK / 4, 256, 0, stream>>>(E, idx_ws, out0);
    code_sum_kernel<<<KCB, 256, 0, stream>>>(z, idx_ws, cs, ea, out3, out4);
    n_kernel<<<1, 1024, 0, stream>>>(out3, n_ws);
    out2_kernel<<<(KCB * DIM) / 256, 256, 0, stream>>>(out4, out3, n_ws, out2);
}